// Round 2
// baseline (10380.984 us; speedup 1.0000x reference)
//
#include <hip/hip_runtime.h>
#include <math.h>

#define NEGD (-1000000000.0)

// ---------------------------------------------------------------------------
// Kernel 0: combined transposed head weights wT[c][o] (f64), o in [0,64):
//   o<48 -> reg_w[o][c], 48<=o<60 -> conf_w[o-48][c], else 0
// ---------------------------------------------------------------------------
__global__ void make_wT(const float* __restrict__ reg_w,
                        const float* __restrict__ conf_w,
                        double* __restrict__ wT)
{
    int i = blockIdx.x * 256 + threadIdx.x;   // over 512*64
    if (i >= 512 * 64) return;
    int c = i >> 6, o = i & 63;
    double v = 0.0;
    if (o < 48)      v = (double)reg_w[o * 512 + c];
    else if (o < 60) v = (double)conf_w[(o - 48) * 512 + c];
    wT[i] = v;
}

// ---------------------------------------------------------------------------
// Kernel 1: 3x3 SAME conv + bias + ReLU, f64 accumulation.
// Processes 4 batches per launch (quarter). Block: 256 thr; tile 64oc x 2row x 64col;
// thread: 8 oc x 4 pix. LDS staged as f64 (ic-chunk 8).
// ---------------------------------------------------------------------------
__global__ __launch_bounds__(256) void conv3x3_relu_f64(
    const float* __restrict__ f, const float* __restrict__ w,
    const float* __restrict__ bias, double* __restrict__ h, int b0)
{
    __shared__ double in_t[8 * 4 * 66];   // [ic(8)][ry 0..3][rx 0..65]
    __shared__ double w_t[64 * 72];       // [oc][ic*9 + k], ic in chunk of 8
    const int bl  = blockIdx.z;           // local batch 0..3
    const int b   = b0 + bl;
    const int oc0 = blockIdx.y * 64;
    const int gy0 = blockIdx.x * 2;
    const int tid = threadIdx.x;
    const int tx  = tid & 31;
    const int og  = tid >> 5;

    double acc[8][4];
#pragma unroll
    for (int j = 0; j < 8; ++j)
#pragma unroll
        for (int i = 0; i < 4; ++i) acc[j][i] = 0.0;

    for (int ic0 = 0; ic0 < 512; ic0 += 8) {
        // stage input chunk (zero-padded halo), f32 -> f64
        for (int e = tid; e < 8 * 4 * 66; e += 256) {
            int ic = e / 264, r = e - ic * 264;
            int ry = r / 66,  rx = r - ry * 66;
            int gy = gy0 + ry - 1, gx = rx - 1;
            double v = 0.0;
            if ((unsigned)gy < 64u && (unsigned)gx < 64u)
                v = (double)f[((b * 512 + ic0 + ic) * 64 + gy) * 64 + gx];
            in_t[e] = v;
        }
        // stage weights chunk, f32 -> f64
        for (int e = tid; e < 64 * 72; e += 256) {
            int oc = e / 72, r = e - oc * 72;
            w_t[e] = (double)w[(oc0 + oc) * 4608 + ic0 * 9 + r];
        }
        __syncthreads();

#pragma unroll 2
        for (int ic = 0; ic < 8; ++ic) {
#pragma unroll
            for (int ky = 0; ky < 3; ++ky) {
#pragma unroll
                for (int kx = 0; kx < 3; ++kx) {
                    double a[4];
#pragma unroll
                    for (int i = 0; i < 4; ++i) {
                        int py = i >> 1, px = tx + 32 * (i & 1);
                        a[i] = in_t[ic * 264 + (py + ky) * 66 + (px + kx)];
                    }
#pragma unroll
                    for (int j = 0; j < 8; ++j) {
                        double wv = w_t[(og * 8 + j) * 72 + ic * 9 + ky * 3 + kx];
#pragma unroll
                        for (int i = 0; i < 4; ++i)
                            acc[j][i] = fma(wv, a[i], acc[j][i]);
                    }
                }
            }
        }
        __syncthreads();
    }

#pragma unroll
    for (int j = 0; j < 8; ++j) {
        int oc = oc0 + og * 8 + j;
        double bz = (double)bias[oc];
#pragma unroll
        for (int i = 0; i < 4; ++i) {
            int py = i >> 1, px = tx + 32 * (i & 1);
            double v = acc[j][i] + bz;
            h[((bl * 512 + oc) * 64 + gy0 + py) * 64 + px] = v > 0.0 ? v : 0.0;
        }
    }
}

// ---------------------------------------------------------------------------
// Kernel 2: head GEMM f64: rc[b][hw][o] = sum_c h[bl][c][hw]*wT[c][o] + bias_o
// Block 256 thr: 128 positions x 64 outputs; thread 8 pos x 4 out.
// ---------------------------------------------------------------------------
__global__ __launch_bounds__(256) void head_gemm_f64(
    const double* __restrict__ h, const double* __restrict__ wT,
    const float* __restrict__ reg_b, const float* __restrict__ conf_b,
    double* __restrict__ rc, int b0)
{
    __shared__ double h_t[32 * 128];
    __shared__ double w_t[32 * 64];
    const int bl  = blockIdx.y;
    const int b   = b0 + bl;
    const int hw0 = blockIdx.x * 128;
    const int tid = threadIdx.x;
    const int to  = tid >> 4;
    const int tp  = tid & 15;

    double acc[8][4];
#pragma unroll
    for (int j = 0; j < 8; ++j)
#pragma unroll
        for (int k = 0; k < 4; ++k) acc[j][k] = 0.0;

    for (int c0 = 0; c0 < 512; c0 += 32) {
        for (int e = tid; e < 32 * 128; e += 256) {
            int c = e >> 7, p = e & 127;
            h_t[e] = h[(bl * 512 + c0 + c) * 4096 + hw0 + p];
        }
        for (int e = tid; e < 32 * 64; e += 256) {
            w_t[e] = wT[(c0 + (e >> 6)) * 64 + (e & 63)];
        }
        __syncthreads();
#pragma unroll 4
        for (int c = 0; c < 32; ++c) {
            double wa[4], hv[8];
#pragma unroll
            for (int k = 0; k < 4; ++k) wa[k] = w_t[c * 64 + to * 4 + k];
#pragma unroll
            for (int j = 0; j < 8; ++j) hv[j] = h_t[c * 128 + tp * 8 + j];
#pragma unroll
            for (int j = 0; j < 8; ++j)
#pragma unroll
                for (int k = 0; k < 4; ++k)
                    acc[j][k] = fma(hv[j], wa[k], acc[j][k]);
        }
        __syncthreads();
    }
#pragma unroll
    for (int k = 0; k < 4; ++k) {
        int o = to * 4 + k;
        double bz = (o < 48) ? (double)reg_b[o] : (o < 60 ? (double)conf_b[o - 48] : 0.0);
#pragma unroll
        for (int j = 0; j < 8; ++j) acc[j][k] += bz;
    }
#pragma unroll
    for (int j = 0; j < 8; ++j)
#pragma unroll
        for (int k = 0; k < 4; ++k)
            rc[(long)(b * 4096 + hw0 + tp * 8 + j) * 64 + to * 4 + k] = acc[j][k];
}

// ---------------------------------------------------------------------------
// Kernel 3: decode anchors+deltas -> clipped boxes (f64), conf, nms score
// Anchors keep the reference's explicit f32 cast points (ws/hs cast, f32 x1..).
// ---------------------------------------------------------------------------
__global__ void decode_f64(const double* __restrict__ rc,
                           double* __restrict__ boxes,
                           double* __restrict__ craw,
                           double* __restrict__ nsc)
{
    int g = blockIdx.x * 256 + threadIdx.x;   // over 16*49152
    if (g >= 16 * 49152) return;
    int b = g / 49152, n = g - b * 49152;
    int hw = n / 12, a = n - hw * 12;
    int y = hw >> 6, x = hw & 63;
    int si = a / 3, ri = a - si * 3;

    double s  = (double)(64 << si);
    double sr = (ri == 0) ? 0.70710678118654752440
              : (ri == 1) ? 1.0 : 1.41421356237309504880;
    float aw = (float)(s * sr);      // reference: np.asarray(ws, np.float32)
    float ah = (float)(s / sr);

    float cyc = ((float)y + 0.5f) * 16.f;   // exact in f32
    float cxc = ((float)x + 0.5f) * 16.f;
    float ax1 = cxc - aw * 0.5f;            // reference anchor build is f32
    float ay1 = cyc - ah * 0.5f;
    float ax2 = cxc + aw * 0.5f;
    float ay2 = cyc + ah * 0.5f;

    double wa  = (double)ax2 - (double)ax1;  // exact from f32 anchors
    double ha  = (double)ay2 - (double)ay1;
    double cxa = (double)ax1 + 0.5 * wa;
    double cya = (double)ay1 + 0.5 * ha;

    const double* r = rc + (long)(b * 4096 + hw) * 64;
    double d0 = r[a * 4 + 0];
    double d1 = r[a * 4 + 1];
    double d2 = r[a * 4 + 2];
    double d3 = r[a * 4 + 3];
    double conf = r[48 + a];

    double pcx = d0 * wa + cxa;
    double pcy = d1 * ha + cya;
    double pw  = wa * exp(d2);
    double ph  = ha * exp(d3);

    double bx1 = pcx - 0.5 * pw;
    double by1 = pcy - 0.5 * ph;
    double bx2 = pcx + 0.5 * pw;
    double by2 = pcy + 0.5 * ph;

    bx1 = fmin(fmax(bx1, 0.0), 1024.0);
    by1 = fmin(fmax(by1, 0.0), 1024.0);
    bx2 = fmin(fmax(bx2, 0.0), 1024.0);
    by2 = fmin(fmax(by2, 0.0), 1024.0);

    double ww = bx2 - bx1, hh = by2 - by1;
    bool valid = (ww >= 1.0) && (hh >= 1.0);

    double* bo = boxes + (long)g * 4;
    bo[0] = bx1; bo[1] = by1; bo[2] = bx2; bo[3] = by2;
    craw[g] = conf;                       // top-k on UNMASKED conf
    nsc[g]  = valid ? conf : NEGD;
}

// ---------------------------------------------------------------------------
// 64-bit order-preserving key
// ---------------------------------------------------------------------------
__device__ __forceinline__ unsigned long long fkey64(double d) {
    unsigned long long u = (unsigned long long)__double_as_longlong(d);
    return (u & 0x8000000000000000ull) ? ~u : (u | 0x8000000000000000ull);
}

// ---------------------------------------------------------------------------
// Kernel 4: per-batch radix select (8 passes) of the 12000th-largest key.
// tinfo[b*2] = threshold key T, tinfo[b*2+1] = E (# of ==T to accept)
// ---------------------------------------------------------------------------
__global__ __launch_bounds__(1024) void topk_thresh64(
    const double* __restrict__ craw, unsigned long long* __restrict__ tinfo)
{
    __shared__ unsigned hist[256];
    __shared__ unsigned long long s_prefix;
    __shared__ int s_k;
    const int b = blockIdx.x, tid = threadIdx.x;
    const double* cb = craw + b * 49152;
    unsigned long long prefix = 0; int k = 12000;
    for (int pass = 0; pass < 8; ++pass) {
        const int shift = 56 - 8 * pass;
        if (tid < 256) hist[tid] = 0;
        __syncthreads();
        for (int i = tid; i < 49152; i += 1024) {
            unsigned long long u = fkey64(cb[i]);
            bool ok = (pass == 0) ||
                      ((u >> (shift + 8)) == (prefix >> (shift + 8)));
            if (ok) atomicAdd(&hist[(unsigned)(u >> shift) & 255u], 1u);
        }
        __syncthreads();
        if (tid == 0) {
            int kk = k, d = 0;
            for (int dd = 255; dd >= 0; --dd) {
                int c = (int)hist[dd];
                if (kk <= c) { d = dd; break; }
                kk -= c;
            }
            s_prefix = prefix | ((unsigned long long)d << shift);
            s_k = kk;
        }
        __syncthreads();
        prefix = s_prefix; k = s_k;
        __syncthreads();
    }
    if (tid == 0) { tinfo[b * 2] = prefix; tinfo[b * 2 + 1] = (unsigned long long)k; }
}

// ---------------------------------------------------------------------------
// Kernel 5: stable (index-order) compaction of top-12000 per batch.
// ---------------------------------------------------------------------------
__global__ __launch_bounds__(1024) void compact_topk64(
    const double* __restrict__ craw, const double* __restrict__ boxes,
    const double* __restrict__ nsc, const unsigned long long* __restrict__ tinfo,
    double* __restrict__ cbox, double* __restrict__ csc)
{
    const int b = blockIdx.x, tid = threadIdx.x;
    const unsigned long long T = tinfo[b * 2];
    const unsigned E = (unsigned)tinfo[b * 2 + 1];
    const double* cb = craw + b * 49152;
    const int i0 = tid * 48;

    unsigned gt = 0, eq = 0;
    for (int j = 0; j < 48; ++j) {
        unsigned long long u = fkey64(cb[i0 + j]);
        gt += (u > T); eq += (u == T);
    }
    unsigned gi = gt, ei = eq;
    for (int d = 1; d < 64; d <<= 1) {
        unsigned g2 = __shfl_up(gi, d), e2 = __shfl_up(ei, d);
        if ((tid & 63) >= d) { gi += g2; ei += e2; }
    }
    __shared__ unsigned wg[16], we[16];
    if ((tid & 63) == 63) { wg[tid >> 6] = gi; we[tid >> 6] = ei; }
    __syncthreads();
    if (tid < 16) {
        unsigned a = wg[tid], c = we[tid];
        for (int d = 1; d < 16; d <<= 1) {
            unsigned a2 = __shfl_up(a, d), c2 = __shfl_up(c, d);
            if (tid >= d) { a += a2; c += c2; }
        }
        wg[tid] = a; we[tid] = c;
    }
    __syncthreads();
    unsigned g = gi - gt + ((tid >> 6) ? wg[(tid >> 6) - 1] : 0u);
    unsigned e = ei - eq + ((tid >> 6) ? we[(tid >> 6) - 1] : 0u);

    double* ob = cbox + (long)b * 12000 * 4;
    double* os = csc  + b * 12000;
    const double* bb = boxes + (long)b * 49152 * 4;
    const double* ns = nsc + b * 49152;
    for (int j = 0; j < 48; ++j) {
        int idx = i0 + j;
        unsigned long long u = fkey64(cb[idx]);
        if (u > T) {
            unsigned pos = g + (e < E ? e : E);
            ob[pos * 4 + 0] = bb[(long)idx * 4 + 0];
            ob[pos * 4 + 1] = bb[(long)idx * 4 + 1];
            ob[pos * 4 + 2] = bb[(long)idx * 4 + 2];
            ob[pos * 4 + 3] = bb[(long)idx * 4 + 3];
            os[pos] = ns[idx];
            ++g;
        } else if (u == T) {
            if (e < E) {
                unsigned pos = g + e;
                ob[pos * 4 + 0] = bb[(long)idx * 4 + 0];
                ob[pos * 4 + 1] = bb[(long)idx * 4 + 1];
                ob[pos * 4 + 2] = bb[(long)idx * 4 + 2];
                ob[pos * 4 + 3] = bb[(long)idx * 4 + 3];
                os[pos] = ns[idx];
            }
            ++e;
        }
    }
}

// ---------------------------------------------------------------------------
// Kernel 6: greedy NMS f64, 256 picks. One 1024-thr block per batch.
// Scores in registers; boxes re-read from global (L2-resident, 384KB/batch).
// ---------------------------------------------------------------------------
__global__ __launch_bounds__(1024) void nms64(
    const double* __restrict__ cbox, const double* __restrict__ csc,
    float* __restrict__ out)
{
    const int b = blockIdx.x, tid = threadIdx.x;
    const double* B4 = cbox + (long)b * 12000 * 4;
    const double* S  = csc  + b * 12000;

    double sc[12];
#pragma unroll
    for (int j = 0; j < 12; ++j) {
        int idx = tid + 1024 * j;
        sc[j] = (idx < 12000) ? S[idx] : NEGD;
    }

    __shared__ double wvv[16];
    __shared__ int    wii[16];
    float* O = out + b * 1024;

    for (int it = 0; it < 256; ++it) {
        double bv = sc[0]; int bj = 0;
#pragma unroll
        for (int j = 1; j < 12; ++j)
            if (sc[j] > bv) { bv = sc[j]; bj = j; }
        int bidx = tid + 1024 * bj;
        for (int d = 1; d < 64; d <<= 1) {
            double ov = __shfl_xor(bv, d);
            int    oi = __shfl_xor(bidx, d);
            if (ov > bv || (ov == bv && oi < bidx)) { bv = ov; bidx = oi; }
        }
        if ((tid & 63) == 0) { wvv[tid >> 6] = bv; wii[tid >> 6] = bidx; }
        __syncthreads();
        if (tid == 0) {
            double v = wvv[0]; int ix = wii[0];
            for (int q = 1; q < 16; ++q)
                if (wvv[q] > v || (wvv[q] == v && wii[q] < ix)) { v = wvv[q]; ix = wii[q]; }
            wvv[0] = v; wii[0] = ix;
        }
        __syncthreads();
        double bestv = wvv[0];
        int    besti = wii[0];
        const double* bb = B4 + (long)besti * 4;
        double b0 = bb[0], b1 = bb[1], b2 = bb[2], b3 = bb[3];
        bool valid = bestv > -5.0e8;
        if (tid == 0) {
            O[it * 4 + 0] = valid ? (float)b0 : 0.f;
            O[it * 4 + 1] = valid ? (float)b1 : 0.f;
            O[it * 4 + 2] = valid ? (float)b2 : 0.f;
            O[it * 4 + 3] = valid ? (float)b3 : 0.f;
        }
        double areaA = (b2 - b0) * (b3 - b1);
#pragma unroll
        for (int j = 0; j < 12; ++j) {
            if (sc[j] > -5.0e8) {
                int idx = tid + 1024 * j;   // sc>NEG implies idx<12000
                const double* pb = B4 + (long)idx * 4;
                double x1 = fmax(b0, pb[0]);
                double y1 = fmax(b1, pb[1]);
                double x2 = fmin(b2, pb[2]);
                double y2 = fmin(b3, pb[3]);
                double iw = x2 - x1; iw = iw > 0.0 ? iw : 0.0;
                double ih = y2 - y1; ih = ih > 0.0 ? ih : 0.0;
                double inter = iw * ih;
                double areaB = (pb[2] - pb[0]) * (pb[3] - pb[1]);
                // iou > 0.7  <=>  inter > 0.7*(areaA+areaB-inter+1e-7)
                if (inter > 0.7 * (areaA + areaB - inter + 1e-7)) sc[j] = NEGD;
            }
        }
        __syncthreads();
    }
}

// ---------------------------------------------------------------------------
// launch
// ---------------------------------------------------------------------------
extern "C" void kernel_launch(void* const* d_in, const int* in_sizes, int n_in,
                              void* d_out, int out_size, void* d_ws, size_t ws_size,
                              hipStream_t stream)
{
    const float* f      = (const float*)d_in[0];
    const float* conv_w = (const float*)d_in[1];
    const float* conv_b = (const float*)d_in[2];
    const float* reg_w  = (const float*)d_in[3];
    const float* reg_b  = (const float*)d_in[4];
    const float* conf_w = (const float*)d_in[5];
    const float* conf_b = (const float*)d_in[6];

    double* ws = (double*)d_ws;
    // double-offset partition (~146.4 MB total)
    double* wT    = ws;                   // 32768
    double* h     = ws + 32768;           // 4*512*4096 = 8388608 (quarter-batch)
    double* rc    = ws + 8421376;         // 65536*64   = 4194304
    double* boxes = ws + 12615680;        // 786432*4   = 3145728
    double* craw  = ws + 15761408;        // 786432
    double* nsc   = ws + 16547840;        // 786432
    double* cbox  = ws + 17334272;        // 192000*4   = 768000
    double* csc   = ws + 18102272;        // 192000
    unsigned long long* tinfo = (unsigned long long*)(ws + 18294272); // 32

    hipLaunchKernelGGL(make_wT, dim3(128), dim3(256), 0, stream, reg_w, conf_w, wT);
    for (int q = 0; q < 4; ++q) {
        int b0 = q * 4;
        hipLaunchKernelGGL(conv3x3_relu_f64, dim3(32, 8, 4), dim3(256), 0, stream,
                           f, conv_w, conv_b, h, b0);
        hipLaunchKernelGGL(head_gemm_f64, dim3(32, 4), dim3(256), 0, stream,
                           h, wT, reg_b, conf_b, rc, b0);
    }
    hipLaunchKernelGGL(decode_f64, dim3(3072), dim3(256), 0, stream,
                       rc, boxes, craw, nsc);
    hipLaunchKernelGGL(topk_thresh64, dim3(16), dim3(1024), 0, stream, craw, tinfo);
    hipLaunchKernelGGL(compact_topk64, dim3(16), dim3(1024), 0, stream,
                       craw, boxes, nsc, tinfo, cbox, csc);
    hipLaunchKernelGGL(nms64, dim3(16), dim3(1024), 0, stream,
                       cbox, csc, (float*)d_out);
}

// Round 4
// 9194.031 us; speedup vs baseline: 1.1291x; 1.1291x over previous
//
#include <hip/hip_runtime.h>
#include <math.h>

#define NEGD (-1000000000.0)

typedef __attribute__((ext_vector_type(4))) double d4;

// ---------------------------------------------------------------------------
// Kernel 0: combined transposed head weights wT[c][o] (f64), o in [0,64):
//   o<48 -> reg_w[o][c], 48<=o<60 -> conf_w[o-48][c], else 0
// ---------------------------------------------------------------------------
__global__ void make_wT(const float* __restrict__ reg_w,
                        const float* __restrict__ conf_w,
                        double* __restrict__ wT)
{
    int i = blockIdx.x * 256 + threadIdx.x;   // over 512*64
    if (i >= 512 * 64) return;
    int c = i >> 6, o = i & 63;
    double v = 0.0;
    if (o < 48)      v = (double)reg_w[o * 512 + c];
    else if (o < 60) v = (double)conf_w[(o - 48) * 512 + c];
    wT[i] = v;
}

// ---------------------------------------------------------------------------
// Kernel 1: 3x3 SAME conv + bias + ReLU via f64 MFMA (implicit GEMM).
// Block 512 thr (8 waves): tile 64 oc x 64 pix (one image row y).
// Wave: 16 oc x 32 pix = 2 MFMA 16x16 tiles. K = ic(512) x 9 taps, MFMA K=4.
// Fragment-layout-independent epilogue: two probe MFMAs decode, per
// (lane,reg), which staged row-label (oc) and col-label (pixel) each D slot
// holds. Correct under any row/col/D-slot label permutation of the f64 MFMA.
// ---------------------------------------------------------------------------
__global__ __launch_bounds__(512, 4) void conv3x3_mfma_f64(
    const float* __restrict__ f, const float* __restrict__ w,
    const float* __restrict__ bias, double* __restrict__ h, int b0)
{
    __shared__ double Xs[8 * 198];   // [ic][ry*66 + cx], cx maps gx=-1..64
    __shared__ double Ws[64 * 73];   // [oc][ic*9 + tap], padded 72->73
    const int bl   = blockIdx.z;     // local batch 0..3
    const int b    = b0 + bl;
    const int oc0  = blockIdx.y * 64;
    const int y    = blockIdx.x;     // image row
    const int tid  = threadIdx.x;
    const int wv   = tid >> 6;
    const int lane = tid & 63;
    const int fk   = lane >> 4;      // assumed k within K=4 group
    const int fm   = lane & 15;      // assumed A row (oc) / B col (pix) label
    const int ocw  = (wv & 3) * 16;  // wave oc base within 64
    const int x0   = (wv >> 2) * 32; // wave pixel base within 64

    // --- layout probes -----------------------------------------------------
    // p1: A supplies its row label, B all-ones  -> D[m][n] = 4*(row label of m)
    // p2: A all-ones, B supplies its col label -> D[m][n] = 4*(col label of n)
    d4 zz = {0.0, 0.0, 0.0, 0.0};
    d4 p1 = __builtin_amdgcn_mfma_f64_16x16x4f64((double)fm, 1.0, zz, 0, 0, 0);
    d4 p2 = __builtin_amdgcn_mfma_f64_16x16x4f64(1.0, (double)fm, zz, 0, 0, 0);
    int ocl[4], pxl[4];
#pragma unroll
    for (int r = 0; r < 4; ++r) {
        ocl[r] = (int)(p1[r] * 0.25);   // staged oc label for this D slot
        pxl[r] = (int)(p2[r] * 0.25);   // staged pixel label for this D slot
    }

    d4 acc0 = {0.0, 0.0, 0.0, 0.0};
    d4 acc1 = {0.0, 0.0, 0.0, 0.0};

    for (int ic0 = 0; ic0 < 512; ic0 += 8) {
        // stage X chunk (zero-padded halo), f32 -> f64, coalesced rows
        for (int e = tid; e < 1584; e += 512) {
            int ic = e / 198, r = e - ic * 198;
            int ry = r / 66, cx = r - ry * 66;
            int gy = y + ry - 1, gx = cx - 1;
            double v = 0.0;
            if ((unsigned)gy < 64u && (unsigned)gx < 64u)
                v = (double)f[((b * 512 + ic0 + ic) * 64 + gy) * 64 + gx];
            Xs[e] = v;
        }
        // stage W chunk, oc-major (coalesced global + conflict-free A reads)
        for (int e = tid; e < 4608; e += 512) {
            int oc = e / 72, it = e - oc * 72;
            Ws[oc * 73 + it] = (double)w[(oc0 + oc) * 4608 + ic0 * 9 + it];
        }
        __syncthreads();

#pragma unroll
        for (int s = 0; s < 2; ++s) {
            const int ick = s * 4 + fk;
            const double* xb = &Xs[ick * 198 + x0 + fm];
            const double* wb = &Ws[(ocw + fm) * 73 + ick * 9];
#pragma unroll
            for (int ky = 0; ky < 3; ++ky) {
#pragma unroll
                for (int kx = 0; kx < 3; ++kx) {
                    double av  = wb[ky * 3 + kx];          // A row-label fm, k slot fk
                    double b0v = xb[ky * 66 + kx];         // B col-label fm -> pixel x0+fm
                    double b1v = xb[ky * 66 + kx + 16];    // col-label fm -> pixel x0+fm+16
                    acc0 = __builtin_amdgcn_mfma_f64_16x16x4f64(av, b0v, acc0, 0, 0, 0);
                    acc1 = __builtin_amdgcn_mfma_f64_16x16x4f64(av, b1v, acc1, 0, 0, 0);
                }
            }
        }
        __syncthreads();
    }

    // probe-decoded epilogue: slot r holds (oc label ocl[r], pixel label pxl[r])
#pragma unroll
    for (int r = 0; r < 4; ++r) {
        int oc = oc0 + ocw + ocl[r];
        double bz = (double)bias[oc];
        double v0 = acc0[r] + bz; v0 = v0 > 0.0 ? v0 : 0.0;
        double v1 = acc1[r] + bz; v1 = v1 > 0.0 ? v1 : 0.0;
        double* hp = &h[(((long)bl * 512 + oc) * 64 + y) * 64];
        hp[x0 + pxl[r]]      = v0;
        hp[x0 + pxl[r] + 16] = v1;
    }
}

// ---------------------------------------------------------------------------
// Kernel 2: head GEMM f64: rc[b][hw][o] = sum_c h[bl][c][hw]*wT[c][o] + bias_o
// ---------------------------------------------------------------------------
__global__ __launch_bounds__(256) void head_gemm_f64(
    const double* __restrict__ h, const double* __restrict__ wT,
    const float* __restrict__ reg_b, const float* __restrict__ conf_b,
    double* __restrict__ rc, int b0)
{
    __shared__ double h_t[32 * 128];
    __shared__ double w_t[32 * 64];
    const int bl  = blockIdx.y;
    const int b   = b0 + bl;
    const int hw0 = blockIdx.x * 128;
    const int tid = threadIdx.x;
    const int to  = tid >> 4;
    const int tp  = tid & 15;

    double acc[8][4];
#pragma unroll
    for (int j = 0; j < 8; ++j)
#pragma unroll
        for (int k = 0; k < 4; ++k) acc[j][k] = 0.0;

    for (int c0 = 0; c0 < 512; c0 += 32) {
        for (int e = tid; e < 32 * 128; e += 256) {
            int c = e >> 7, p = e & 127;
            h_t[e] = h[(bl * 512 + c0 + c) * 4096 + hw0 + p];
        }
        for (int e = tid; e < 32 * 64; e += 256) {
            w_t[e] = wT[(c0 + (e >> 6)) * 64 + (e & 63)];
        }
        __syncthreads();
#pragma unroll 4
        for (int c = 0; c < 32; ++c) {
            double wa[4], hv[8];
#pragma unroll
            for (int k = 0; k < 4; ++k) wa[k] = w_t[c * 64 + to * 4 + k];
#pragma unroll
            for (int j = 0; j < 8; ++j) hv[j] = h_t[c * 128 + tp * 8 + j];
#pragma unroll
            for (int j = 0; j < 8; ++j)
#pragma unroll
                for (int k = 0; k < 4; ++k)
                    acc[j][k] = fma(hv[j], wa[k], acc[j][k]);
        }
        __syncthreads();
    }
#pragma unroll
    for (int k = 0; k < 4; ++k) {
        int o = to * 4 + k;
        double bz = (o < 48) ? (double)reg_b[o] : (o < 60 ? (double)conf_b[o - 48] : 0.0);
#pragma unroll
        for (int j = 0; j < 8; ++j) acc[j][k] += bz;
    }
#pragma unroll
    for (int j = 0; j < 8; ++j)
#pragma unroll
        for (int k = 0; k < 4; ++k)
            rc[(long)(b * 4096 + hw0 + tp * 8 + j) * 64 + to * 4 + k] = acc[j][k];
}

// ---------------------------------------------------------------------------
// Kernel 3: decode anchors+deltas -> clipped boxes (f64), conf, nms score
// ---------------------------------------------------------------------------
__global__ void decode_f64(const double* __restrict__ rc,
                           double* __restrict__ boxes,
                           double* __restrict__ craw,
                           double* __restrict__ nsc)
{
    int g = blockIdx.x * 256 + threadIdx.x;   // over 16*49152
    if (g >= 16 * 49152) return;
    int b = g / 49152, n = g - b * 49152;
    int hw = n / 12, a = n - hw * 12;
    int y = hw >> 6, x = hw & 63;
    int si = a / 3, ri = a - si * 3;

    double s  = (double)(64 << si);
    double sr = (ri == 0) ? 0.70710678118654752440
              : (ri == 1) ? 1.0 : 1.41421356237309504880;
    float aw = (float)(s * sr);      // reference: np.asarray(ws, np.float32)
    float ah = (float)(s / sr);

    float cyc = ((float)y + 0.5f) * 16.f;   // exact in f32
    float cxc = ((float)x + 0.5f) * 16.f;
    float ax1 = cxc - aw * 0.5f;            // reference anchor build is f32
    float ay1 = cyc - ah * 0.5f;
    float ax2 = cxc + aw * 0.5f;
    float ay2 = cyc + ah * 0.5f;

    double wa  = (double)ax2 - (double)ax1;  // exact from f32 anchors
    double ha  = (double)ay2 - (double)ay1;
    double cxa = (double)ax1 + 0.5 * wa;
    double cya = (double)ay1 + 0.5 * ha;

    const double* r = rc + (long)(b * 4096 + hw) * 64;
    double d0 = r[a * 4 + 0];
    double d1 = r[a * 4 + 1];
    double d2 = r[a * 4 + 2];
    double d3 = r[a * 4 + 3];
    double conf = r[48 + a];

    double pcx = d0 * wa + cxa;
    double pcy = d1 * ha + cya;
    double pw  = wa * exp(d2);
    double ph  = ha * exp(d3);

    double bx1 = pcx - 0.5 * pw;
    double by1 = pcy - 0.5 * ph;
    double bx2 = pcx + 0.5 * pw;
    double by2 = pcy + 0.5 * ph;

    bx1 = fmin(fmax(bx1, 0.0), 1024.0);
    by1 = fmin(fmax(by1, 0.0), 1024.0);
    bx2 = fmin(fmax(bx2, 0.0), 1024.0);
    by2 = fmin(fmax(by2, 0.0), 1024.0);

    double ww = bx2 - bx1, hh = by2 - by1;
    bool valid = (ww >= 1.0) && (hh >= 1.0);

    double* bo = boxes + (long)g * 4;
    bo[0] = bx1; bo[1] = by1; bo[2] = bx2; bo[3] = by2;
    craw[g] = conf;                       // top-k on UNMASKED conf
    nsc[g]  = valid ? conf : NEGD;
}

// ---------------------------------------------------------------------------
// 64-bit order-preserving key
// ---------------------------------------------------------------------------
__device__ __forceinline__ unsigned long long fkey64(double d) {
    unsigned long long u = (unsigned long long)__double_as_longlong(d);
    return (u & 0x8000000000000000ull) ? ~u : (u | 0x8000000000000000ull);
}

// ---------------------------------------------------------------------------
// Kernel 4: per-batch radix select (8 passes) of the 12000th-largest key.
// ---------------------------------------------------------------------------
__global__ __launch_bounds__(1024) void topk_thresh64(
    const double* __restrict__ craw, unsigned long long* __restrict__ tinfo)
{
    __shared__ unsigned hist[256];
    __shared__ unsigned long long s_prefix;
    __shared__ int s_k;
    const int b = blockIdx.x, tid = threadIdx.x;
    const double* cb = craw + b * 49152;
    unsigned long long prefix = 0; int k = 12000;
    for (int pass = 0; pass < 8; ++pass) {
        const int shift = 56 - 8 * pass;
        if (tid < 256) hist[tid] = 0;
        __syncthreads();
        for (int i = tid; i < 49152; i += 1024) {
            unsigned long long u = fkey64(cb[i]);
            bool ok = (pass == 0) ||
                      ((u >> (shift + 8)) == (prefix >> (shift + 8)));
            if (ok) atomicAdd(&hist[(unsigned)(u >> shift) & 255u], 1u);
        }
        __syncthreads();
        if (tid == 0) {
            int kk = k, d = 0;
            for (int dd = 255; dd >= 0; --dd) {
                int c = (int)hist[dd];
                if (kk <= c) { d = dd; break; }
                kk -= c;
            }
            s_prefix = prefix | ((unsigned long long)d << shift);
            s_k = kk;
        }
        __syncthreads();
        prefix = s_prefix; k = s_k;
        __syncthreads();
    }
    if (tid == 0) { tinfo[b * 2] = prefix; tinfo[b * 2 + 1] = (unsigned long long)k; }
}

// ---------------------------------------------------------------------------
// Kernel 5: stable (index-order) compaction of top-12000 per batch.
// ---------------------------------------------------------------------------
__global__ __launch_bounds__(1024) void compact_topk64(
    const double* __restrict__ craw, const double* __restrict__ boxes,
    const double* __restrict__ nsc, const unsigned long long* __restrict__ tinfo,
    double* __restrict__ cbox, double* __restrict__ csc)
{
    const int b = blockIdx.x, tid = threadIdx.x;
    const unsigned long long T = tinfo[b * 2];
    const unsigned E = (unsigned)tinfo[b * 2 + 1];
    const double* cb = craw + b * 49152;
    const int i0 = tid * 48;

    unsigned gt = 0, eq = 0;
    for (int j = 0; j < 48; ++j) {
        unsigned long long u = fkey64(cb[i0 + j]);
        gt += (u > T); eq += (u == T);
    }
    unsigned gi = gt, ei = eq;
    for (int d = 1; d < 64; d <<= 1) {
        unsigned g2 = __shfl_up(gi, d), e2 = __shfl_up(ei, d);
        if ((tid & 63) >= d) { gi += g2; ei += e2; }
    }
    __shared__ unsigned wg[16], we[16];
    if ((tid & 63) == 63) { wg[tid >> 6] = gi; we[tid >> 6] = ei; }
    __syncthreads();
    if (tid < 16) {
        unsigned a = wg[tid], c = we[tid];
        for (int d = 1; d < 16; d <<= 1) {
            unsigned a2 = __shfl_up(a, d), c2 = __shfl_up(c, d);
            if (tid >= d) { a += a2; c += c2; }
        }
        wg[tid] = a; we[tid] = c;
    }
    __syncthreads();
    unsigned g = gi - gt + ((tid >> 6) ? wg[(tid >> 6) - 1] : 0u);
    unsigned e = ei - eq + ((tid >> 6) ? we[(tid >> 6) - 1] : 0u);

    double* ob = cbox + (long)b * 12000 * 4;
    double* os = csc  + b * 12000;
    const double* bb = boxes + (long)b * 49152 * 4;
    const double* ns = nsc + b * 49152;
    for (int j = 0; j < 48; ++j) {
        int idx = i0 + j;
        unsigned long long u = fkey64(cb[idx]);
        if (u > T) {
            unsigned pos = g + (e < E ? e : E);
            ob[pos * 4 + 0] = bb[(long)idx * 4 + 0];
            ob[pos * 4 + 1] = bb[(long)idx * 4 + 1];
            ob[pos * 4 + 2] = bb[(long)idx * 4 + 2];
            ob[pos * 4 + 3] = bb[(long)idx * 4 + 3];
            os[pos] = ns[idx];
            ++g;
        } else if (u == T) {
            if (e < E) {
                unsigned pos = g + e;
                ob[pos * 4 + 0] = bb[(long)idx * 4 + 0];
                ob[pos * 4 + 1] = bb[(long)idx * 4 + 1];
                ob[pos * 4 + 2] = bb[(long)idx * 4 + 2];
                ob[pos * 4 + 3] = bb[(long)idx * 4 + 3];
                os[pos] = ns[idx];
            }
            ++e;
        }
    }
}

// ---------------------------------------------------------------------------
// Kernel 6: greedy NMS f64, 256 picks. One 1024-thr block per batch.
// ---------------------------------------------------------------------------
__global__ __launch_bounds__(1024) void nms64(
    const double* __restrict__ cbox, const double* __restrict__ csc,
    float* __restrict__ out)
{
    const int b = blockIdx.x, tid = threadIdx.x;
    const double* B4 = cbox + (long)b * 12000 * 4;
    const double* S  = csc  + b * 12000;

    double sc[12];
#pragma unroll
    for (int j = 0; j < 12; ++j) {
        int idx = tid + 1024 * j;
        sc[j] = (idx < 12000) ? S[idx] : NEGD;
    }

    __shared__ double wvv[16];
    __shared__ int    wii[16];
    float* O = out + b * 1024;

    for (int it = 0; it < 256; ++it) {
        double bv = sc[0]; int bj = 0;
#pragma unroll
        for (int j = 1; j < 12; ++j)
            if (sc[j] > bv) { bv = sc[j]; bj = j; }
        int bidx = tid + 1024 * bj;
        for (int d = 1; d < 64; d <<= 1) {
            double ov = __shfl_xor(bv, d);
            int    oi = __shfl_xor(bidx, d);
            if (ov > bv || (ov == bv && oi < bidx)) { bv = ov; bidx = oi; }
        }
        if ((tid & 63) == 0) { wvv[tid >> 6] = bv; wii[tid >> 6] = bidx; }
        __syncthreads();
        if (tid == 0) {
            double v = wvv[0]; int ix = wii[0];
            for (int q = 1; q < 16; ++q)
                if (wvv[q] > v || (wvv[q] == v && wii[q] < ix)) { v = wvv[q]; ix = wii[q]; }
            wvv[0] = v; wii[0] = ix;
        }
        __syncthreads();
        double bestv = wvv[0];
        int    besti = wii[0];
        const double* bb = B4 + (long)besti * 4;
        double b0 = bb[0], b1 = bb[1], b2 = bb[2], b3 = bb[3];
        bool valid = bestv > -5.0e8;
        if (tid == 0) {
            O[it * 4 + 0] = valid ? (float)b0 : 0.f;
            O[it * 4 + 1] = valid ? (float)b1 : 0.f;
            O[it * 4 + 2] = valid ? (float)b2 : 0.f;
            O[it * 4 + 3] = valid ? (float)b3 : 0.f;
        }
        double areaA = (b2 - b0) * (b3 - b1);
#pragma unroll
        for (int j = 0; j < 12; ++j) {
            if (sc[j] > -5.0e8) {
                int idx = tid + 1024 * j;
                const double* pb = B4 + (long)idx * 4;
                double x1 = fmax(b0, pb[0]);
                double y1 = fmax(b1, pb[1]);
                double x2 = fmin(b2, pb[2]);
                double y2 = fmin(b3, pb[3]);
                double iw = x2 - x1; iw = iw > 0.0 ? iw : 0.0;
                double ih = y2 - y1; ih = ih > 0.0 ? ih : 0.0;
                double inter = iw * ih;
                double areaB = (pb[2] - pb[0]) * (pb[3] - pb[1]);
                if (inter > 0.7 * (areaA + areaB - inter + 1e-7)) sc[j] = NEGD;
            }
        }
        __syncthreads();
    }
}

// ---------------------------------------------------------------------------
// launch
// ---------------------------------------------------------------------------
extern "C" void kernel_launch(void* const* d_in, const int* in_sizes, int n_in,
                              void* d_out, int out_size, void* d_ws, size_t ws_size,
                              hipStream_t stream)
{
    const float* f      = (const float*)d_in[0];
    const float* conv_w = (const float*)d_in[1];
    const float* conv_b = (const float*)d_in[2];
    const float* reg_w  = (const float*)d_in[3];
    const float* reg_b  = (const float*)d_in[4];
    const float* conf_w = (const float*)d_in[5];
    const float* conf_b = (const float*)d_in[6];

    double* ws = (double*)d_ws;
    // double-offset partition (~146.4 MB total)
    double* wT    = ws;                   // 32768
    double* h     = ws + 32768;           // 4*512*4096 = 8388608 (quarter-batch)
    double* rc    = ws + 8421376;         // 65536*64   = 4194304
    double* boxes = ws + 12615680;        // 786432*4   = 3145728
    double* craw  = ws + 15761408;        // 786432
    double* nsc   = ws + 16547840;        // 786432
    double* cbox  = ws + 17334272;        // 192000*4   = 768000
    double* csc   = ws + 18102272;        // 192000
    unsigned long long* tinfo = (unsigned long long*)(ws + 18294272); // 32

    hipLaunchKernelGGL(make_wT, dim3(128), dim3(256), 0, stream, reg_w, conf_w, wT);
    for (int q = 0; q < 4; ++q) {
        int b0 = q * 4;
        hipLaunchKernelGGL(conv3x3_mfma_f64, dim3(64, 8, 4), dim3(512), 0, stream,
                           f, conv_w, conv_b, h, b0);
        hipLaunchKernelGGL(head_gemm_f64, dim3(32, 4), dim3(256), 0, stream,
                           h, wT, reg_b, conf_b, rc, b0);
    }
    hipLaunchKernelGGL(decode_f64, dim3(3072), dim3(256), 0, stream,
                       rc, boxes, craw, nsc);
    hipLaunchKernelGGL(topk_thresh64, dim3(16), dim3(1024), 0, stream, craw, tinfo);
    hipLaunchKernelGGL(compact_topk64, dim3(16), dim3(1024), 0, stream,
                       craw, boxes, nsc, tinfo, cbox, csc);
    hipLaunchKernelGGL(nms64, dim3(16), dim3(1024), 0, stream,
                       cbox, csc, (float*)d_out);
}

// Round 5
// 8490.041 us; speedup vs baseline: 1.2227x; 1.0829x over previous
//
#include <hip/hip_runtime.h>
#include <math.h>

#define NEGD (-1000000000.0)

typedef __attribute__((ext_vector_type(4))) double d4;
typedef __attribute__((ext_vector_type(2))) double d2;

// ---------------------------------------------------------------------------
// Kernel -1: convert conv weights f32 -> f64 (once; enables aligned d2 staging)
// ---------------------------------------------------------------------------
__global__ void convert_w64(const float* __restrict__ w, double* __restrict__ w64)
{
    int i = blockIdx.x * 1024 + threadIdx.x;   // over 512*4608 = 2359296
    if (i < 2359296) w64[i] = (double)w[i];
}

// ---------------------------------------------------------------------------
// Kernel 0: combined transposed head weights wT[c][o] (f64), o in [0,64):
//   o<48 -> reg_w[o][c], 48<=o<60 -> conf_w[o-48][c], else 0
// ---------------------------------------------------------------------------
__global__ void make_wT(const float* __restrict__ reg_w,
                        const float* __restrict__ conf_w,
                        double* __restrict__ wT)
{
    int i = blockIdx.x * 256 + threadIdx.x;   // over 512*64
    if (i >= 512 * 64) return;
    int c = i >> 6, o = i & 63;
    double v = 0.0;
    if (o < 48)      v = (double)reg_w[o * 512 + c];
    else if (o < 60) v = (double)conf_w[(o - 48) * 512 + c];
    wT[i] = v;
}

// ---------------------------------------------------------------------------
// Kernel 1: 3x3 SAME conv + bias + ReLU via f64 MFMA (implicit GEMM).
// Block 256 thr (4 waves): tile 32 oc x 128 pix (2 rows x 64 cols).
// Wave: 32 oc x 32 pix = 2x2 MFMA tiles -> each ds_read feeds 2 MFMAs.
// LDS: Xs[8ic][4ry][66] 16.9KB + Ws[32oc][74] 18.9KB = 35.8KB -> 4 blocks/CU.
// Probe-decoded epilogue (layout-independent, verified r4).
// ---------------------------------------------------------------------------
__global__ __launch_bounds__(256, 4) void conv3x3_mfma_f64(
    const float* __restrict__ f, const double* __restrict__ w64,
    const float* __restrict__ bias, double* __restrict__ h, int b0)
{
    __shared__ double Xs[8 * 264];   // [ic][ry*66 + cx], cx maps gx=-1..64
    __shared__ double Ws[32 * 74];   // [oc][ic*9 + tap], pad 72->74 (16B-aligned, 2-way free)
    const int bl   = blockIdx.z;     // local batch 0..3
    const int b    = b0 + bl;
    const int oc0  = blockIdx.y * 32;
    const int y0   = blockIdx.x * 2; // two image rows per block
    const int tid  = threadIdx.x;
    const int wv   = tid >> 6;
    const int lane = tid & 63;
    const int fk   = lane >> 4;      // k slot within K=4
    const int fm   = lane & 15;      // A row / B col label
    const int ryo  = wv >> 1;        // wave image row (0..1)
    const int xb0  = (wv & 1) * 32;  // wave col base

    // --- layout probes (decode D-slot -> (row label, col label)) ----------
    d4 zz = {0.0, 0.0, 0.0, 0.0};
    d4 p1 = __builtin_amdgcn_mfma_f64_16x16x4f64((double)fm, 1.0, zz, 0, 0, 0);
    d4 p2 = __builtin_amdgcn_mfma_f64_16x16x4f64(1.0, (double)fm, zz, 0, 0, 0);
    int ocl[4], pxl[4];
#pragma unroll
    for (int r = 0; r < 4; ++r) {
        ocl[r] = (int)(p1[r] * 0.25);
        pxl[r] = (int)(p2[r] * 0.25);
    }

    d4 a00 = zz, a01 = zz, a10 = zz, a11 = zz;

    for (int ic0 = 0; ic0 < 512; ic0 += 8) {
        // stage X chunk (zero-padded halo), f32 -> f64
        for (int e = tid; e < 2112; e += 256) {
            int ic = e / 264, r = e - ic * 264;
            int ry = r / 66, cx = r - ry * 66;
            int gy = y0 + ry - 1, gx = cx - 1;
            double v = 0.0;
            if ((unsigned)gy < 64u && (unsigned)gx < 64u)
                v = (double)f[((b * 512 + ic0 + ic) * 64 + gy) * 64 + gx];
            Xs[e] = v;
        }
        // stage W chunk from pre-converted f64, aligned double2 copies
        for (int e = tid; e < 1152; e += 256) {
            int oc = e / 36, jj = (e - oc * 36) * 2;
            d2 v = *(const d2*)&w64[(size_t)(oc0 + oc) * 4608 + ic0 * 9 + jj];
            *(d2*)&Ws[oc * 74 + jj] = v;
        }
        __syncthreads();

#pragma unroll
        for (int s = 0; s < 2; ++s) {
            const int ick = s * 4 + fk;
            const double* xr  = &Xs[ick * 264 + ryo * 66 + xb0 + fm];
            const double* wr0 = &Ws[fm * 74 + ick * 9];
            const double* wr1 = &Ws[(fm + 16) * 74 + ick * 9];
#pragma unroll
            for (int ky = 0; ky < 3; ++ky) {
#pragma unroll
                for (int kx = 0; kx < 3; ++kx) {
                    double a0v = wr0[ky * 3 + kx];
                    double a1v = wr1[ky * 3 + kx];
                    double b0v = xr[ky * 66 + kx];
                    double b1v = xr[ky * 66 + kx + 16];
                    a00 = __builtin_amdgcn_mfma_f64_16x16x4f64(a0v, b0v, a00, 0, 0, 0);
                    a01 = __builtin_amdgcn_mfma_f64_16x16x4f64(a0v, b1v, a01, 0, 0, 0);
                    a10 = __builtin_amdgcn_mfma_f64_16x16x4f64(a1v, b0v, a10, 0, 0, 0);
                    a11 = __builtin_amdgcn_mfma_f64_16x16x4f64(a1v, b1v, a11, 0, 0, 0);
                }
            }
        }
        __syncthreads();
    }

    // probe-decoded epilogue
    const int y = y0 + ryo;
#pragma unroll
    for (int r = 0; r < 4; ++r) {
        int ocA = oc0 + ocl[r];
        int ocB = oc0 + 16 + ocl[r];
        int px0 = xb0 + pxl[r];
        double bzA = (double)bias[ocA];
        double bzB = (double)bias[ocB];
        double v00 = a00[r] + bzA; v00 = v00 > 0.0 ? v00 : 0.0;
        double v01 = a01[r] + bzA; v01 = v01 > 0.0 ? v01 : 0.0;
        double v10 = a10[r] + bzB; v10 = v10 > 0.0 ? v10 : 0.0;
        double v11 = a11[r] + bzB; v11 = v11 > 0.0 ? v11 : 0.0;
        double* hA = &h[(((long)bl * 512 + ocA) * 64 + y) * 64];
        double* hB = &h[(((long)bl * 512 + ocB) * 64 + y) * 64];
        hA[px0]      = v00;
        hA[px0 + 16] = v01;
        hB[px0]      = v10;
        hB[px0 + 16] = v11;
    }
}

// ---------------------------------------------------------------------------
// Kernel 2: head GEMM f64: rc[b][hw][o] = sum_c h[bl][c][hw]*wT[c][o] + bias_o
// ---------------------------------------------------------------------------
__global__ __launch_bounds__(256) void head_gemm_f64(
    const double* __restrict__ h, const double* __restrict__ wT,
    const float* __restrict__ reg_b, const float* __restrict__ conf_b,
    double* __restrict__ rc, int b0)
{
    __shared__ double h_t[32 * 128];
    __shared__ double w_t[32 * 64];
    const int bl  = blockIdx.y;
    const int b   = b0 + bl;
    const int hw0 = blockIdx.x * 128;
    const int tid = threadIdx.x;
    const int to  = tid >> 4;
    const int tp  = tid & 15;

    double acc[8][4];
#pragma unroll
    for (int j = 0; j < 8; ++j)
#pragma unroll
        for (int k = 0; k < 4; ++k) acc[j][k] = 0.0;

    for (int c0 = 0; c0 < 512; c0 += 32) {
        for (int e = tid; e < 32 * 128; e += 256) {
            int c = e >> 7, p = e & 127;
            h_t[e] = h[(bl * 512 + c0 + c) * 4096 + hw0 + p];
        }
        for (int e = tid; e < 32 * 64; e += 256) {
            w_t[e] = wT[(c0 + (e >> 6)) * 64 + (e & 63)];
        }
        __syncthreads();
#pragma unroll 4
        for (int c = 0; c < 32; ++c) {
            double wa[4], hv[8];
#pragma unroll
            for (int k = 0; k < 4; ++k) wa[k] = w_t[c * 64 + to * 4 + k];
#pragma unroll
            for (int j = 0; j < 8; ++j) hv[j] = h_t[c * 128 + tp * 8 + j];
#pragma unroll
            for (int j = 0; j < 8; ++j)
#pragma unroll
                for (int k = 0; k < 4; ++k)
                    acc[j][k] = fma(hv[j], wa[k], acc[j][k]);
        }
        __syncthreads();
    }
#pragma unroll
    for (int k = 0; k < 4; ++k) {
        int o = to * 4 + k;
        double bz = (o < 48) ? (double)reg_b[o] : (o < 60 ? (double)conf_b[o - 48] : 0.0);
#pragma unroll
        for (int j = 0; j < 8; ++j) acc[j][k] += bz;
    }
#pragma unroll
    for (int j = 0; j < 8; ++j)
#pragma unroll
        for (int k = 0; k < 4; ++k)
            rc[(long)(b * 4096 + hw0 + tp * 8 + j) * 64 + to * 4 + k] = acc[j][k];
}

// ---------------------------------------------------------------------------
// Kernel 3: decode anchors+deltas -> clipped boxes (f64), conf, nms score
// ---------------------------------------------------------------------------
__global__ void decode_f64(const double* __restrict__ rc,
                           double* __restrict__ boxes,
                           double* __restrict__ craw,
                           double* __restrict__ nsc)
{
    int g = blockIdx.x * 256 + threadIdx.x;   // over 16*49152
    if (g >= 16 * 49152) return;
    int b = g / 49152, n = g - b * 49152;
    int hw = n / 12, a = n - hw * 12;
    int y = hw >> 6, x = hw & 63;
    int si = a / 3, ri = a - si * 3;

    double s  = (double)(64 << si);
    double sr = (ri == 0) ? 0.70710678118654752440
              : (ri == 1) ? 1.0 : 1.41421356237309504880;
    float aw = (float)(s * sr);      // reference: np.asarray(ws, np.float32)
    float ah = (float)(s / sr);

    float cyc = ((float)y + 0.5f) * 16.f;   // exact in f32
    float cxc = ((float)x + 0.5f) * 16.f;
    float ax1 = cxc - aw * 0.5f;            // reference anchor build is f32
    float ay1 = cyc - ah * 0.5f;
    float ax2 = cxc + aw * 0.5f;
    float ay2 = cyc + ah * 0.5f;

    double wa  = (double)ax2 - (double)ax1;  // exact from f32 anchors
    double ha  = (double)ay2 - (double)ay1;
    double cxa = (double)ax1 + 0.5 * wa;
    double cya = (double)ay1 + 0.5 * ha;

    const double* r = rc + (long)(b * 4096 + hw) * 64;
    double d0 = r[a * 4 + 0];
    double d1 = r[a * 4 + 1];
    double d2v = r[a * 4 + 2];
    double d3 = r[a * 4 + 3];
    double conf = r[48 + a];

    double pcx = d0 * wa + cxa;
    double pcy = d1 * ha + cya;
    double pw  = wa * exp(d2v);
    double ph  = ha * exp(d3);

    double bx1 = pcx - 0.5 * pw;
    double by1 = pcy - 0.5 * ph;
    double bx2 = pcx + 0.5 * pw;
    double by2 = pcy + 0.5 * ph;

    bx1 = fmin(fmax(bx1, 0.0), 1024.0);
    by1 = fmin(fmax(by1, 0.0), 1024.0);
    bx2 = fmin(fmax(bx2, 0.0), 1024.0);
    by2 = fmin(fmax(by2, 0.0), 1024.0);

    double ww = bx2 - bx1, hh = by2 - by1;
    bool valid = (ww >= 1.0) && (hh >= 1.0);

    double* bo = boxes + (long)g * 4;
    bo[0] = bx1; bo[1] = by1; bo[2] = bx2; bo[3] = by2;
    craw[g] = conf;                       // top-k on UNMASKED conf
    nsc[g]  = valid ? conf : NEGD;
}

// ---------------------------------------------------------------------------
// 64-bit order-preserving key
// ---------------------------------------------------------------------------
__device__ __forceinline__ unsigned long long fkey64(double d) {
    unsigned long long u = (unsigned long long)__double_as_longlong(d);
    return (u & 0x8000000000000000ull) ? ~u : (u | 0x8000000000000000ull);
}

// ---------------------------------------------------------------------------
// Kernel 4: per-batch radix select (8 passes) of the 12000th-largest key.
// ---------------------------------------------------------------------------
__global__ __launch_bounds__(1024) void topk_thresh64(
    const double* __restrict__ craw, unsigned long long* __restrict__ tinfo)
{
    __shared__ unsigned hist[256];
    __shared__ unsigned long long s_prefix;
    __shared__ int s_k;
    const int b = blockIdx.x, tid = threadIdx.x;
    const double* cb = craw + b * 49152;
    unsigned long long prefix = 0; int k = 12000;
    for (int pass = 0; pass < 8; ++pass) {
        const int shift = 56 - 8 * pass;
        if (tid < 256) hist[tid] = 0;
        __syncthreads();
        for (int i = tid; i < 49152; i += 1024) {
            unsigned long long u = fkey64(cb[i]);
            bool ok = (pass == 0) ||
                      ((u >> (shift + 8)) == (prefix >> (shift + 8)));
            if (ok) atomicAdd(&hist[(unsigned)(u >> shift) & 255u], 1u);
        }
        __syncthreads();
        if (tid == 0) {
            int kk = k, d = 0;
            for (int dd = 255; dd >= 0; --dd) {
                int c = (int)hist[dd];
                if (kk <= c) { d = dd; break; }
                kk -= c;
            }
            s_prefix = prefix | ((unsigned long long)d << shift);
            s_k = kk;
        }
        __syncthreads();
        prefix = s_prefix; k = s_k;
        __syncthreads();
    }
    if (tid == 0) { tinfo[b * 2] = prefix; tinfo[b * 2 + 1] = (unsigned long long)k; }
}

// ---------------------------------------------------------------------------
// Kernel 5: stable (index-order) compaction of top-12000 per batch.
// ---------------------------------------------------------------------------
__global__ __launch_bounds__(1024) void compact_topk64(
    const double* __restrict__ craw, const double* __restrict__ boxes,
    const double* __restrict__ nsc, const unsigned long long* __restrict__ tinfo,
    double* __restrict__ cbox, double* __restrict__ csc)
{
    const int b = blockIdx.x, tid = threadIdx.x;
    const unsigned long long T = tinfo[b * 2];
    const unsigned E = (unsigned)tinfo[b * 2 + 1];
    const double* cb = craw + b * 49152;
    const int i0 = tid * 48;

    unsigned gt = 0, eq = 0;
    for (int j = 0; j < 48; ++j) {
        unsigned long long u = fkey64(cb[i0 + j]);
        gt += (u > T); eq += (u == T);
    }
    unsigned gi = gt, ei = eq;
    for (int d = 1; d < 64; d <<= 1) {
        unsigned g2 = __shfl_up(gi, d), e2 = __shfl_up(ei, d);
        if ((tid & 63) >= d) { gi += g2; ei += e2; }
    }
    __shared__ unsigned wg[16], we[16];
    if ((tid & 63) == 63) { wg[tid >> 6] = gi; we[tid >> 6] = ei; }
    __syncthreads();
    if (tid < 16) {
        unsigned a = wg[tid], c = we[tid];
        for (int d = 1; d < 16; d <<= 1) {
            unsigned a2 = __shfl_up(a, d), c2 = __shfl_up(c, d);
            if (tid >= d) { a += a2; c += c2; }
        }
        wg[tid] = a; we[tid] = c;
    }
    __syncthreads();
    unsigned g = gi - gt + ((tid >> 6) ? wg[(tid >> 6) - 1] : 0u);
    unsigned e = ei - eq + ((tid >> 6) ? we[(tid >> 6) - 1] : 0u);

    double* ob = cbox + (long)b * 12000 * 4;
    double* os = csc  + b * 12000;
    const double* bb = boxes + (long)b * 49152 * 4;
    const double* ns = nsc + b * 49152;
    for (int j = 0; j < 48; ++j) {
        int idx = i0 + j;
        unsigned long long u = fkey64(cb[idx]);
        if (u > T) {
            unsigned pos = g + (e < E ? e : E);
            ob[pos * 4 + 0] = bb[(long)idx * 4 + 0];
            ob[pos * 4 + 1] = bb[(long)idx * 4 + 1];
            ob[pos * 4 + 2] = bb[(long)idx * 4 + 2];
            ob[pos * 4 + 3] = bb[(long)idx * 4 + 3];
            os[pos] = ns[idx];
            ++g;
        } else if (u == T) {
            if (e < E) {
                unsigned pos = g + e;
                ob[pos * 4 + 0] = bb[(long)idx * 4 + 0];
                ob[pos * 4 + 1] = bb[(long)idx * 4 + 1];
                ob[pos * 4 + 2] = bb[(long)idx * 4 + 2];
                ob[pos * 4 + 3] = bb[(long)idx * 4 + 3];
                os[pos] = ns[idx];
            }
            ++e;
        }
    }
}

// ---------------------------------------------------------------------------
// Kernel 6: greedy NMS f64, 256 picks. One 1024-thr block per batch.
// ---------------------------------------------------------------------------
__global__ __launch_bounds__(1024) void nms64(
    const double* __restrict__ cbox, const double* __restrict__ csc,
    float* __restrict__ out)
{
    const int b = blockIdx.x, tid = threadIdx.x;
    const double* B4 = cbox + (long)b * 12000 * 4;
    const double* S  = csc  + b * 12000;

    double sc[12];
#pragma unroll
    for (int j = 0; j < 12; ++j) {
        int idx = tid + 1024 * j;
        sc[j] = (idx < 12000) ? S[idx] : NEGD;
    }

    __shared__ double wvv[16];
    __shared__ int    wii[16];
    float* O = out + b * 1024;

    for (int it = 0; it < 256; ++it) {
        double bv = sc[0]; int bj = 0;
#pragma unroll
        for (int j = 1; j < 12; ++j)
            if (sc[j] > bv) { bv = sc[j]; bj = j; }
        int bidx = tid + 1024 * bj;
        for (int d = 1; d < 64; d <<= 1) {
            double ov = __shfl_xor(bv, d);
            int    oi = __shfl_xor(bidx, d);
            if (ov > bv || (ov == bv && oi < bidx)) { bv = ov; bidx = oi; }
        }
        if ((tid & 63) == 0) { wvv[tid >> 6] = bv; wii[tid >> 6] = bidx; }
        __syncthreads();
        if (tid == 0) {
            double v = wvv[0]; int ix = wii[0];
            for (int q = 1; q < 16; ++q)
                if (wvv[q] > v || (wvv[q] == v && wii[q] < ix)) { v = wvv[q]; ix = wii[q]; }
            wvv[0] = v; wii[0] = ix;
        }
        __syncthreads();
        double bestv = wvv[0];
        int    besti = wii[0];
        const double* bb = B4 + (long)besti * 4;
        double b0 = bb[0], b1 = bb[1], b2 = bb[2], b3 = bb[3];
        bool valid = bestv > -5.0e8;
        if (tid == 0) {
            O[it * 4 + 0] = valid ? (float)b0 : 0.f;
            O[it * 4 + 1] = valid ? (float)b1 : 0.f;
            O[it * 4 + 2] = valid ? (float)b2 : 0.f;
            O[it * 4 + 3] = valid ? (float)b3 : 0.f;
        }
        double areaA = (b2 - b0) * (b3 - b1);
#pragma unroll
        for (int j = 0; j < 12; ++j) {
            if (sc[j] > -5.0e8) {
                int idx = tid + 1024 * j;
                const double* pb = B4 + (long)idx * 4;
                double x1 = fmax(b0, pb[0]);
                double y1 = fmax(b1, pb[1]);
                double x2 = fmin(b2, pb[2]);
                double y2 = fmin(b3, pb[3]);
                double iw = x2 - x1; iw = iw > 0.0 ? iw : 0.0;
                double ih = y2 - y1; ih = ih > 0.0 ? ih : 0.0;
                double inter = iw * ih;
                double areaB = (pb[2] - pb[0]) * (pb[3] - pb[1]);
                if (inter > 0.7 * (areaA + areaB - inter + 1e-7)) sc[j] = NEGD;
            }
        }
        __syncthreads();
    }
}

// ---------------------------------------------------------------------------
// launch
// ---------------------------------------------------------------------------
extern "C" void kernel_launch(void* const* d_in, const int* in_sizes, int n_in,
                              void* d_out, int out_size, void* d_ws, size_t ws_size,
                              hipStream_t stream)
{
    const float* f      = (const float*)d_in[0];
    const float* conv_w = (const float*)d_in[1];
    const float* conv_b = (const float*)d_in[2];
    const float* reg_w  = (const float*)d_in[3];
    const float* reg_b  = (const float*)d_in[4];
    const float* conf_w = (const float*)d_in[5];
    const float* conf_b = (const float*)d_in[6];

    double* ws = (double*)d_ws;
    // double-offset partition (~146.4 MB total)
    double* wT    = ws;                   // 32768
    double* h     = ws + 32768;           // 4*512*4096 = 8388608 (quarter-batch)
    double* rc    = ws + 8421376;         // 65536*64   = 4194304
    double* boxes = ws + 12615680;        // 786432*4   = 3145728
    double* craw  = ws + 15761408;        // 786432
    double* nsc   = ws + 16547840;        // 786432
    double* cbox  = ws + 17334272;        // 192000*4   = 768000
    double* csc   = ws + 18102272;        // 192000
    unsigned long long* tinfo = (unsigned long long*)(ws + 18294272); // 32
    // w64 (512*4608 = 2359296 doubles) OVERLAYS the boxes region (3145728
    // doubles): conv reads w64 strictly before decode_f64 writes boxes.
    double* w64   = boxes;

    hipLaunchKernelGGL(convert_w64, dim3(2304), dim3(1024), 0, stream, conv_w, w64);
    hipLaunchKernelGGL(make_wT, dim3(128), dim3(256), 0, stream, reg_w, conf_w, wT);
    for (int q = 0; q < 4; ++q) {
        int b0 = q * 4;
        hipLaunchKernelGGL(conv3x3_mfma_f64, dim3(32, 16, 4), dim3(256), 0, stream,
                           f, w64, conv_b, h, b0);
        hipLaunchKernelGGL(head_gemm_f64, dim3(32, 4), dim3(256), 0, stream,
                           h, wT, reg_b, conf_b, rc, b0);
    }
    hipLaunchKernelGGL(decode_f64, dim3(3072), dim3(256), 0, stream,
                       rc, boxes, craw, nsc);
    hipLaunchKernelGGL(topk_thresh64, dim3(16), dim3(1024), 0, stream, craw, tinfo);
    hipLaunchKernelGGL(compact_topk64, dim3(16), dim3(1024), 0, stream,
                       craw, boxes, nsc, tinfo, cbox, csc);
    hipLaunchKernelGGL(nms64, dim3(16), dim3(1024), 0, stream,
                       cbox, csc, (float*)d_out);
}

// Round 6
// 7516.450 us; speedup vs baseline: 1.3811x; 1.1295x over previous
//
#include <hip/hip_runtime.h>
#include <math.h>

#define NEGD (-1000000000.0)

typedef __attribute__((ext_vector_type(4))) double d4;

// ---------------------------------------------------------------------------
// Kernel -1: transpose+convert conv weights to f64: w64t[(ic*9+tap)*512 + oc]
// ---------------------------------------------------------------------------
__global__ void convert_w64t(const float* __restrict__ w, double* __restrict__ w64t)
{
    int i = blockIdx.x * 1024 + threadIdx.x;   // over 512*4608 = 2359296
    if (i >= 2359296) return;
    int c9t = i >> 9, oc = i & 511;
    w64t[i] = (double)w[oc * 4608 + c9t];
}

// ---------------------------------------------------------------------------
// Kernel 0: combined transposed head weights wT[c][o] (f64), o in [0,64):
//   o<48 -> reg_w[o][c], 48<=o<60 -> conf_w[o-48][c], else 0
// ---------------------------------------------------------------------------
__global__ void make_wT(const float* __restrict__ reg_w,
                        const float* __restrict__ conf_w,
                        double* __restrict__ wT)
{
    int i = blockIdx.x * 256 + threadIdx.x;   // over 512*64
    if (i >= 512 * 64) return;
    int c = i >> 6, o = i & 63;
    double v = 0.0;
    if (o < 48)      v = (double)reg_w[o * 512 + c];
    else if (o < 60) v = (double)conf_w[(o - 48) * 512 + c];
    wT[i] = v;
}

// ---------------------------------------------------------------------------
// Kernel 1: 3x3 SAME conv + bias + ReLU via f64 MFMA (implicit GEMM).
// Block 256 thr (4 waves): tile 32 oc x 128 pix (2 rows x 64 cols).
// Wave: 32 oc x 32 pix = 2x2 MFMA 16x16x4 tiles.
// DOUBLE-BUFFERED: ic-chunk 4, reg-prefetch chunk k+1 during MFMA of k,
// one barrier per chunk. LDS 2x(Xs 8.4KB + Ws 9.2KB) = 34.5KB -> 4 blk/CU.
// Ws layout [j=ic*9+tap][oc] with rotation swizzle col'=(oc+8*ic)&31 ->
// A-reads land 2 lanes/double-bank (free). Probe-decoded epilogue (r4).
// ---------------------------------------------------------------------------
__global__ __launch_bounds__(256, 4) void conv3x3_mfma_f64(
    const float* __restrict__ f, const double* __restrict__ w64t,
    const float* __restrict__ bias, double* __restrict__ h, int b0)
{
    __shared__ double Xs[2][1056];   // [buf][ic(4)][ry(4)][cx(66)]
    __shared__ double Ws[2][1152];   // [buf][j(36)][oc(32) rotated]
    const int bl   = blockIdx.z;     // local batch 0..3
    const int b    = b0 + bl;
    const int oc0  = blockIdx.y * 32;
    const int y0   = blockIdx.x * 2; // two image rows per block
    const int tid  = threadIdx.x;
    const int wv   = tid >> 6;
    const int lane = tid & 63;
    const int fk   = lane >> 4;      // k slot within K=4 (= local ic)
    const int fm   = lane & 15;      // A row / B col label
    const int ryo  = wv >> 1;        // wave image row (0..1)
    const int xb0  = (wv & 1) * 32;  // wave col base
    const int c0r  = (fm + 8 * fk) & 31;        // rotated col, oc=fm
    const int c1r  = (fm + 16 + 8 * fk) & 31;   // rotated col, oc=fm+16

    // --- layout probes (decode D-slot -> (row label, col label)) ----------
    d4 zz = {0.0, 0.0, 0.0, 0.0};
    d4 p1 = __builtin_amdgcn_mfma_f64_16x16x4f64((double)fm, 1.0, zz, 0, 0, 0);
    d4 p2 = __builtin_amdgcn_mfma_f64_16x16x4f64(1.0, (double)fm, zz, 0, 0, 0);
    int ocl[4], pxl[4];
#pragma unroll
    for (int r = 0; r < 4; ++r) {
        ocl[r] = (int)(p1[r] * 0.25);
        pxl[r] = (int)(p2[r] * 0.25);
    }

    d4 a00 = zz, a01 = zz, a10 = zz, a11 = zz;

    double xreg[5], wreg[5];

    auto load_chunk = [&](int kc) {
#pragma unroll
        for (int i = 0; i < 5; ++i) {
            int e = tid + 256 * i;
            double v = 0.0;
            if (e < 1056) {
                int ic = e / 264, r = e - ic * 264;
                int ry = r / 66, cx = r - ry * 66;
                int gy = y0 + ry - 1, gx = cx - 1;
                if ((unsigned)gy < 64u && (unsigned)gx < 64u)
                    v = (double)f[((b * 512 + kc * 4 + ic) * 64 + gy) * 64 + gx];
            }
            xreg[i] = v;
        }
#pragma unroll
        for (int i = 0; i < 5; ++i) {
            int e = tid + 256 * i;
            if (e < 1152) {
                int j = e >> 5, oc = e & 31;
                wreg[i] = w64t[(size_t)(kc * 36 + j) * 512 + oc0 + oc];
            }
        }
    };
    auto write_chunk = [&](int buf) {
#pragma unroll
        for (int i = 0; i < 5; ++i) {
            int e = tid + 256 * i;
            if (e < 1056) Xs[buf][e] = xreg[i];
        }
#pragma unroll
        for (int i = 0; i < 5; ++i) {
            int e = tid + 256 * i;
            if (e < 1152) {
                int j = e >> 5, oc = e & 31;
                Ws[buf][j * 32 + ((oc + 8 * (j / 9)) & 31)] = wreg[i];
            }
        }
    };
    auto compute_chunk = [&](int buf) {
        const double* Xb = &Xs[buf][fk * 264 + ryo * 66 + xb0 + fm];
        const double* Wb = &Ws[buf][fk * 288];   // (fk*9)*32
#pragma unroll
        for (int t = 0; t < 9; ++t) {
            const int ky = t / 3, kx = t - ky * 3;
            double a0v = Wb[t * 32 + c0r];
            double a1v = Wb[t * 32 + c1r];
            double b0v = Xb[ky * 66 + kx];
            double b1v = Xb[ky * 66 + kx + 16];
            a00 = __builtin_amdgcn_mfma_f64_16x16x4f64(a0v, b0v, a00, 0, 0, 0);
            a01 = __builtin_amdgcn_mfma_f64_16x16x4f64(a0v, b1v, a01, 0, 0, 0);
            a10 = __builtin_amdgcn_mfma_f64_16x16x4f64(a1v, b0v, a10, 0, 0, 0);
            a11 = __builtin_amdgcn_mfma_f64_16x16x4f64(a1v, b1v, a11, 0, 0, 0);
        }
    };

    // prologue: stage chunk 0
    load_chunk(0);
    write_chunk(0);
    __syncthreads();

    for (int k = 0; k < 128; ++k) {
        const int cur = k & 1;
        if (k < 127) load_chunk(k + 1);    // issue globals early (hidden by MFMA)
        compute_chunk(cur);
        if (k < 127) write_chunk(cur ^ 1); // vmcnt drain happens here anyway
        __syncthreads();
    }

    // probe-decoded epilogue
    const int y = y0 + ryo;
#pragma unroll
    for (int r = 0; r < 4; ++r) {
        int ocA = oc0 + ocl[r];
        int ocB = oc0 + 16 + ocl[r];
        int px0 = xb0 + pxl[r];
        double bzA = (double)bias[ocA];
        double bzB = (double)bias[ocB];
        double v00 = a00[r] + bzA; v00 = v00 > 0.0 ? v00 : 0.0;
        double v01 = a01[r] + bzA; v01 = v01 > 0.0 ? v01 : 0.0;
        double v10 = a10[r] + bzB; v10 = v10 > 0.0 ? v10 : 0.0;
        double v11 = a11[r] + bzB; v11 = v11 > 0.0 ? v11 : 0.0;
        double* hA = &h[(((long)bl * 512 + ocA) * 64 + y) * 64];
        double* hB = &h[(((long)bl * 512 + ocB) * 64 + y) * 64];
        hA[px0]      = v00;
        hA[px0 + 16] = v01;
        hB[px0]      = v10;
        hB[px0 + 16] = v11;
    }
}

// ---------------------------------------------------------------------------
// Kernel 2: head GEMM f64: rc[b][hw][o] = sum_c h[bl][c][hw]*wT[c][o] + bias_o
// ---------------------------------------------------------------------------
__global__ __launch_bounds__(256) void head_gemm_f64(
    const double* __restrict__ h, const double* __restrict__ wT,
    const float* __restrict__ reg_b, const float* __restrict__ conf_b,
    double* __restrict__ rc, int b0)
{
    __shared__ double h_t[32 * 128];
    __shared__ double w_t[32 * 64];
    const int bl  = blockIdx.y;
    const int b   = b0 + bl;
    const int hw0 = blockIdx.x * 128;
    const int tid = threadIdx.x;
    const int to  = tid >> 4;
    const int tp  = tid & 15;

    double acc[8][4];
#pragma unroll
    for (int j = 0; j < 8; ++j)
#pragma unroll
        for (int k = 0; k < 4; ++k) acc[j][k] = 0.0;

    for (int c0 = 0; c0 < 512; c0 += 32) {
        for (int e = tid; e < 32 * 128; e += 256) {
            int c = e >> 7, p = e & 127;
            h_t[e] = h[(bl * 512 + c0 + c) * 4096 + hw0 + p];
        }
        for (int e = tid; e < 32 * 64; e += 256) {
            w_t[e] = wT[(c0 + (e >> 6)) * 64 + (e & 63)];
        }
        __syncthreads();
#pragma unroll 4
        for (int c = 0; c < 32; ++c) {
            double wa[4], hv[8];
#pragma unroll
            for (int k = 0; k < 4; ++k) wa[k] = w_t[c * 64 + to * 4 + k];
#pragma unroll
            for (int j = 0; j < 8; ++j) hv[j] = h_t[c * 128 + tp * 8 + j];
#pragma unroll
            for (int j = 0; j < 8; ++j)
#pragma unroll
                for (int k = 0; k < 4; ++k)
                    acc[j][k] = fma(hv[j], wa[k], acc[j][k]);
        }
        __syncthreads();
    }
#pragma unroll
    for (int k = 0; k < 4; ++k) {
        int o = to * 4 + k;
        double bz = (o < 48) ? (double)reg_b[o] : (o < 60 ? (double)conf_b[o - 48] : 0.0);
#pragma unroll
        for (int j = 0; j < 8; ++j) acc[j][k] += bz;
    }
#pragma unroll
    for (int j = 0; j < 8; ++j)
#pragma unroll
        for (int k = 0; k < 4; ++k)
            rc[(long)(b * 4096 + hw0 + tp * 8 + j) * 64 + to * 4 + k] = acc[j][k];
}

// ---------------------------------------------------------------------------
// Kernel 3: decode anchors+deltas -> clipped boxes (f64), conf, nms score
// ---------------------------------------------------------------------------
__global__ void decode_f64(const double* __restrict__ rc,
                           double* __restrict__ boxes,
                           double* __restrict__ craw,
                           double* __restrict__ nsc)
{
    int g = blockIdx.x * 256 + threadIdx.x;   // over 16*49152
    if (g >= 16 * 49152) return;
    int b = g / 49152, n = g - b * 49152;
    int hw = n / 12, a = n - hw * 12;
    int y = hw >> 6, x = hw & 63;
    int si = a / 3, ri = a - si * 3;

    double s  = (double)(64 << si);
    double sr = (ri == 0) ? 0.70710678118654752440
              : (ri == 1) ? 1.0 : 1.41421356237309504880;
    float aw = (float)(s * sr);      // reference: np.asarray(ws, np.float32)
    float ah = (float)(s / sr);

    float cyc = ((float)y + 0.5f) * 16.f;   // exact in f32
    float cxc = ((float)x + 0.5f) * 16.f;
    float ax1 = cxc - aw * 0.5f;            // reference anchor build is f32
    float ay1 = cyc - ah * 0.5f;
    float ax2 = cxc + aw * 0.5f;
    float ay2 = cyc + ah * 0.5f;

    double wa  = (double)ax2 - (double)ax1;  // exact from f32 anchors
    double ha  = (double)ay2 - (double)ay1;
    double cxa = (double)ax1 + 0.5 * wa;
    double cya = (double)ay1 + 0.5 * ha;

    const double* r = rc + (long)(b * 4096 + hw) * 64;
    double d0 = r[a * 4 + 0];
    double d1 = r[a * 4 + 1];
    double d2v = r[a * 4 + 2];
    double d3 = r[a * 4 + 3];
    double conf = r[48 + a];

    double pcx = d0 * wa + cxa;
    double pcy = d1 * ha + cya;
    double pw  = wa * exp(d2v);
    double ph  = ha * exp(d3);

    double bx1 = pcx - 0.5 * pw;
    double by1 = pcy - 0.5 * ph;
    double bx2 = pcx + 0.5 * pw;
    double by2 = pcy + 0.5 * ph;

    bx1 = fmin(fmax(bx1, 0.0), 1024.0);
    by1 = fmin(fmax(by1, 0.0), 1024.0);
    bx2 = fmin(fmax(bx2, 0.0), 1024.0);
    by2 = fmin(fmax(by2, 0.0), 1024.0);

    double ww = bx2 - bx1, hh = by2 - by1;
    bool valid = (ww >= 1.0) && (hh >= 1.0);

    double* bo = boxes + (long)g * 4;
    bo[0] = bx1; bo[1] = by1; bo[2] = bx2; bo[3] = by2;
    craw[g] = conf;                       // top-k on UNMASKED conf
    nsc[g]  = valid ? conf : NEGD;
}

// ---------------------------------------------------------------------------
// 64-bit order-preserving key
// ---------------------------------------------------------------------------
__device__ __forceinline__ unsigned long long fkey64(double d) {
    unsigned long long u = (unsigned long long)__double_as_longlong(d);
    return (u & 0x8000000000000000ull) ? ~u : (u | 0x8000000000000000ull);
}

// ---------------------------------------------------------------------------
// Kernel 4: per-batch radix select (8 passes) of the 12000th-largest key.
// ---------------------------------------------------------------------------
__global__ __launch_bounds__(1024) void topk_thresh64(
    const double* __restrict__ craw, unsigned long long* __restrict__ tinfo)
{
    __shared__ unsigned hist[256];
    __shared__ unsigned long long s_prefix;
    __shared__ int s_k;
    const int b = blockIdx.x, tid = threadIdx.x;
    const double* cb = craw + b * 49152;
    unsigned long long prefix = 0; int k = 12000;
    for (int pass = 0; pass < 8; ++pass) {
        const int shift = 56 - 8 * pass;
        if (tid < 256) hist[tid] = 0;
        __syncthreads();
        for (int i = tid; i < 49152; i += 1024) {
            unsigned long long u = fkey64(cb[i]);
            bool ok = (pass == 0) ||
                      ((u >> (shift + 8)) == (prefix >> (shift + 8)));
            if (ok) atomicAdd(&hist[(unsigned)(u >> shift) & 255u], 1u);
        }
        __syncthreads();
        if (tid == 0) {
            int kk = k, d = 0;
            for (int dd = 255; dd >= 0; --dd) {
                int c = (int)hist[dd];
                if (kk <= c) { d = dd; break; }
                kk -= c;
            }
            s_prefix = prefix | ((unsigned long long)d << shift);
            s_k = kk;
        }
        __syncthreads();
        prefix = s_prefix; k = s_k;
        __syncthreads();
    }
    if (tid == 0) { tinfo[b * 2] = prefix; tinfo[b * 2 + 1] = (unsigned long long)k; }
}

// ---------------------------------------------------------------------------
// Kernel 5: stable (index-order) compaction of top-12000 per batch.
// ---------------------------------------------------------------------------
__global__ __launch_bounds__(1024) void compact_topk64(
    const double* __restrict__ craw, const double* __restrict__ boxes,
    const double* __restrict__ nsc, const unsigned long long* __restrict__ tinfo,
    double* __restrict__ cbox, double* __restrict__ csc)
{
    const int b = blockIdx.x, tid = threadIdx.x;
    const unsigned long long T = tinfo[b * 2];
    const unsigned E = (unsigned)tinfo[b * 2 + 1];
    const double* cb = craw + b * 49152;
    const int i0 = tid * 48;

    unsigned gt = 0, eq = 0;
    for (int j = 0; j < 48; ++j) {
        unsigned long long u = fkey64(cb[i0 + j]);
        gt += (u > T); eq += (u == T);
    }
    unsigned gi = gt, ei = eq;
    for (int d = 1; d < 64; d <<= 1) {
        unsigned g2 = __shfl_up(gi, d), e2 = __shfl_up(ei, d);
        if ((tid & 63) >= d) { gi += g2; ei += e2; }
    }
    __shared__ unsigned wg[16], we[16];
    if ((tid & 63) == 63) { wg[tid >> 6] = gi; we[tid >> 6] = ei; }
    __syncthreads();
    if (tid < 16) {
        unsigned a = wg[tid], c = we[tid];
        for (int d = 1; d < 16; d <<= 1) {
            unsigned a2 = __shfl_up(a, d), c2 = __shfl_up(c, d);
            if (tid >= d) { a += a2; c += c2; }
        }
        wg[tid] = a; we[tid] = c;
    }
    __syncthreads();
    unsigned g = gi - gt + ((tid >> 6) ? wg[(tid >> 6) - 1] : 0u);
    unsigned e = ei - eq + ((tid >> 6) ? we[(tid >> 6) - 1] : 0u);

    double* ob = cbox + (long)b * 12000 * 4;
    double* os = csc  + b * 12000;
    const double* bb = boxes + (long)b * 49152 * 4;
    const double* ns = nsc + b * 49152;
    for (int j = 0; j < 48; ++j) {
        int idx = i0 + j;
        unsigned long long u = fkey64(cb[idx]);
        if (u > T) {
            unsigned pos = g + (e < E ? e : E);
            ob[pos * 4 + 0] = bb[(long)idx * 4 + 0];
            ob[pos * 4 + 1] = bb[(long)idx * 4 + 1];
            ob[pos * 4 + 2] = bb[(long)idx * 4 + 2];
            ob[pos * 4 + 3] = bb[(long)idx * 4 + 3];
            os[pos] = ns[idx];
            ++g;
        } else if (u == T) {
            if (e < E) {
                unsigned pos = g + e;
                ob[pos * 4 + 0] = bb[(long)idx * 4 + 0];
                ob[pos * 4 + 1] = bb[(long)idx * 4 + 1];
                ob[pos * 4 + 2] = bb[(long)idx * 4 + 2];
                ob[pos * 4 + 3] = bb[(long)idx * 4 + 3];
                os[pos] = ns[idx];
            }
            ++e;
        }
    }
}

// ---------------------------------------------------------------------------
// Kernel 6: greedy NMS f64, 256 picks. One 1024-thr block per batch.
// ---------------------------------------------------------------------------
__global__ __launch_bounds__(1024) void nms64(
    const double* __restrict__ cbox, const double* __restrict__ csc,
    float* __restrict__ out)
{
    const int b = blockIdx.x, tid = threadIdx.x;
    const double* B4 = cbox + (long)b * 12000 * 4;
    const double* S  = csc  + b * 12000;

    double sc[12];
#pragma unroll
    for (int j = 0; j < 12; ++j) {
        int idx = tid + 1024 * j;
        sc[j] = (idx < 12000) ? S[idx] : NEGD;
    }

    __shared__ double wvv[16];
    __shared__ int    wii[16];
    float* O = out + b * 1024;

    for (int it = 0; it < 256; ++it) {
        double bv = sc[0]; int bj = 0;
#pragma unroll
        for (int j = 1; j < 12; ++j)
            if (sc[j] > bv) { bv = sc[j]; bj = j; }
        int bidx = tid + 1024 * bj;
        for (int d = 1; d < 64; d <<= 1) {
            double ov = __shfl_xor(bv, d);
            int    oi = __shfl_xor(bidx, d);
            if (ov > bv || (ov == bv && oi < bidx)) { bv = ov; bidx = oi; }
        }
        if ((tid & 63) == 0) { wvv[tid >> 6] = bv; wii[tid >> 6] = bidx; }
        __syncthreads();
        if (tid == 0) {
            double v = wvv[0]; int ix = wii[0];
            for (int q = 1; q < 16; ++q)
                if (wvv[q] > v || (wvv[q] == v && wii[q] < ix)) { v = wvv[q]; ix = wii[q]; }
            wvv[0] = v; wii[0] = ix;
        }
        __syncthreads();
        double bestv = wvv[0];
        int    besti = wii[0];
        const double* bb = B4 + (long)besti * 4;
        double b0 = bb[0], b1 = bb[1], b2 = bb[2], b3 = bb[3];
        bool valid = bestv > -5.0e8;
        if (tid == 0) {
            O[it * 4 + 0] = valid ? (float)b0 : 0.f;
            O[it * 4 + 1] = valid ? (float)b1 : 0.f;
            O[it * 4 + 2] = valid ? (float)b2 : 0.f;
            O[it * 4 + 3] = valid ? (float)b3 : 0.f;
        }
        double areaA = (b2 - b0) * (b3 - b1);
#pragma unroll
        for (int j = 0; j < 12; ++j) {
            if (sc[j] > -5.0e8) {
                int idx = tid + 1024 * j;
                const double* pb = B4 + (long)idx * 4;
                double x1 = fmax(b0, pb[0]);
                double y1 = fmax(b1, pb[1]);
                double x2 = fmin(b2, pb[2]);
                double y2 = fmin(b3, pb[3]);
                double iw = x2 - x1; iw = iw > 0.0 ? iw : 0.0;
                double ih = y2 - y1; ih = ih > 0.0 ? ih : 0.0;
                double inter = iw * ih;
                double areaB = (pb[2] - pb[0]) * (pb[3] - pb[1]);
                if (inter > 0.7 * (areaA + areaB - inter + 1e-7)) sc[j] = NEGD;
            }
        }
        __syncthreads();
    }
}

// ---------------------------------------------------------------------------
// launch
// ---------------------------------------------------------------------------
extern "C" void kernel_launch(void* const* d_in, const int* in_sizes, int n_in,
                              void* d_out, int out_size, void* d_ws, size_t ws_size,
                              hipStream_t stream)
{
    const float* f      = (const float*)d_in[0];
    const float* conv_w = (const float*)d_in[1];
    const float* conv_b = (const float*)d_in[2];
    const float* reg_w  = (const float*)d_in[3];
    const float* reg_b  = (const float*)d_in[4];
    const float* conf_w = (const float*)d_in[5];
    const float* conf_b = (const float*)d_in[6];

    double* ws = (double*)d_ws;
    // double-offset partition (~146.4 MB total)
    double* wT    = ws;                   // 32768
    double* h     = ws + 32768;           // 4*512*4096 = 8388608 (quarter-batch)
    double* rc    = ws + 8421376;         // 65536*64   = 4194304
    double* boxes = ws + 12615680;        // 786432*4   = 3145728
    double* craw  = ws + 15761408;        // 786432
    double* nsc   = ws + 16547840;        // 786432
    double* cbox  = ws + 17334272;        // 192000*4   = 768000
    double* csc   = ws + 18102272;        // 192000
    unsigned long long* tinfo = (unsigned long long*)(ws + 18294272); // 32
    // w64t (2359296 doubles) OVERLAYS the boxes region (3145728 doubles):
    // conv reads w64t strictly before decode_f64 writes boxes.
    double* w64t  = boxes;

    hipLaunchKernelGGL(convert_w64t, dim3(2304), dim3(1024), 0, stream, conv_w, w64t);
    hipLaunchKernelGGL(make_wT, dim3(128), dim3(256), 0, stream, reg_w, conf_w, wT);
    for (int q = 0; q < 4; ++q) {
        int b0 = q * 4;
        hipLaunchKernelGGL(conv3x3_mfma_f64, dim3(32, 16, 4), dim3(256), 0, stream,
                           f, w64t, conv_b, h, b0);
        hipLaunchKernelGGL(head_gemm_f64, dim3(32, 4), dim3(256), 0, stream,
                           h, wT, reg_b, conf_b, rc, b0);
    }
    hipLaunchKernelGGL(decode_f64, dim3(3072), dim3(256), 0, stream,
                       rc, boxes, craw, nsc);
    hipLaunchKernelGGL(topk_thresh64, dim3(16), dim3(1024), 0, stream, craw, tinfo);
    hipLaunchKernelGGL(compact_topk64, dim3(16), dim3(1024), 0, stream,
                       craw, boxes, nsc, tinfo, cbox, csc);
    hipLaunchKernelGGL(nms64, dim3(16), dim3(1024), 0, stream,
                       cbox, csc, (float*)d_out);
}